// Round 7
// baseline (1496.677 us; speedup 1.0000x reference)
//
#include <hip/hip_runtime.h>
#include <cstdint>
#include <cstddef>

typedef unsigned short u16;
typedef unsigned int u32;

typedef __bf16 bf16x8 __attribute__((ext_vector_type(8)));
typedef float f32x4 __attribute__((ext_vector_type(4)));

__device__ __forceinline__ float bf2f(u16 v) { return __builtin_bit_cast(float, (u32)v << 16); }
__device__ __forceinline__ u16 f2bf(float f) {
    u32 u = __builtin_bit_cast(u32, f);
    u += 0x7fffu + ((u >> 16) & 1u);   // RNE
    return (u16)(u >> 16);
}
__device__ __forceinline__ bf16x8 ld8(const u16* p) {
    return __builtin_bit_cast(bf16x8, *(const uint4*)p);
}
__device__ __forceinline__ u32 cvtpk(float lo, float hi) {
    u32 r;
    asm("v_cvt_pk_bf16_f32 %0, %1, %2" : "=v"(r) : "v"(lo), "v"(hi));
    return r;
}
__device__ __forceinline__ void glds16(const u16* g, u16* l) {
    __builtin_amdgcn_global_load_lds((const __attribute__((address_space(1))) void*)g,
                                     (__attribute__((address_space(3))) void*)l, 16, 0, 0);
}

// Bias selector: up to 4 pointer segments of 1024 floats each, indexed by n>>10.
struct B4 { const float* p[4]; };

// ---------------------------------------------------------------------------
// float32 -> bf16 elementwise convert (x -> Hb). n/1024 blocks of 256.
// ---------------------------------------------------------------------------
__global__ __launch_bounds__(256) void conv_f2b(const float* __restrict__ src,
                                                u16* __restrict__ dst)
{
    int idx = blockIdx.x * 256 + threadIdx.x;
    float4 v = ((const float4*)src)[idx];
    uint2 o;
    o.x = (u32)f2bf(v.x) | ((u32)f2bf(v.y) << 16);
    o.y = (u32)f2bf(v.z) | ((u32)f2bf(v.w) << 16);
    ((uint2*)dst)[idx] = o;
}

// ---------------------------------------------------------------------------
// GEMM: C = act( A[M,K] @ B[K,N] + bias[n] (+ R) ), A row-major bf16, B given
// TRANSPOSED bf16 (Bt element (n,k) at (n>>6)*nbs + (n&63)*ldb + k), bias via
// B4 segments (p[n>>10][n&1023], f32).
// C/R address: (m&1023)*crow + (m>>10)*cbatch + (n>>6)*chead + (n&63).
// M = gridDim.y*BM, N = gridDim.x*BN exactly; K multiple of 64.
//
// K-loop: BK=64, double-buffered LDS, prefetch-issue before compute (one
// barrier per K-tile; its vmcnt-drain lands after the compute phase, hiding
// the load latency). LDS layout XOR-swizzled (rule: linear glds dest +
// inverse-swizzled GLOBAL source col + swizzled ds_read addr):
//   staging lane l of a wave covers (row=l>>3, 16B-blk=l&7) holding global
//   col-blk (l&7)^(l>>3); fragment read of global blk X at row uses LDS blk
//   X^(row&7). 16 read lanes spread over 8 bank-groups = 2-way = free.
// ---------------------------------------------------------------------------
template <int BM, int BN>
__global__ __launch_bounds__(256) void gemm_bt(
    const u16* __restrict__ A, int lda,
    const u16* __restrict__ Bt, int ldb, int nbs,
    B4 bias,
    const u16* __restrict__ Rres,
    u16* __restrict__ C, int crow, int cbatch, int chead,
    int K, int relu)
{
    constexpr int WM = BM / 2, WN = BN / 2, FM = WM / 16, FN = WN / 16;
    __shared__ __align__(16) u16 Ald[2][BM * 64];
    __shared__ __align__(16) u16 Bld[2][BN * 64];
    const int tid = threadIdx.x;
    const int w = tid >> 6, lane = tid & 63;
    const int qd = lane >> 4, r = lane & 15;
    const int wr = w >> 1, wc = w & 1;
    const int m0 = blockIdx.y * BM, n0 = blockIdx.x * BN;
    // staging: one glds16 per wave covers 8 rows x 64 cols (16B per lane)
    const int srow = lane >> 3;                        // row within 8-row stripe
    const int scol = ((lane ^ (lane >> 3)) & 7) * 8;   // inverse-swizzled src col

    auto stage = [&](int buf, int k0) {
#pragma unroll
        for (int ii = 0; ii < BM / 32; ++ii) {
            int rbase = w * (BM / 4) + ii * 8;
            glds16(A + (long)(m0 + rbase + srow) * lda + k0 + scol,
                   &Ald[buf][rbase * 64]);
        }
#pragma unroll
        for (int ii = 0; ii < BN / 32; ++ii) {
            int nbase = w * (BN / 4) + ii * 8;
            int ng = n0 + nbase + srow;
            glds16(Bt + (long)(ng >> 6) * nbs + (long)(ng & 63) * ldb + k0 + scol,
                   &Bld[buf][nbase * 64]);
        }
    };

    f32x4 acc[FM][FN] = {};
    const int nt = K >> 6;

    stage(0, 0);
    __syncthreads();   // drains prologue stage (vmcnt) per barrier semantics

    for (int t = 0; t < nt; ++t) {
        const int cur = t & 1;
        if (t + 1 < nt) stage(cur ^ 1, (t + 1) << 6);   // prefetch next tile
#pragma unroll
        for (int s = 0; s < 2; ++s) {
            bf16x8 af[FM], bb[FN];
#pragma unroll
            for (int fm = 0; fm < FM; ++fm) {
                int row = wr * WM + fm * 16 + r;
                int blk = ((s << 2) | qd) ^ (r & 7);
                af[fm] = ld8(&Ald[cur][row * 64 + blk * 8]);
            }
#pragma unroll
            for (int fn = 0; fn < FN; ++fn) {
                int row = wc * WN + fn * 16 + r;
                int blk = ((s << 2) | qd) ^ (r & 7);
                bb[fn] = ld8(&Bld[cur][row * 64 + blk * 8]);
            }
#pragma unroll
            for (int fm = 0; fm < FM; ++fm)
#pragma unroll
                for (int fn = 0; fn < FN; ++fn)
                    acc[fm][fn] = __builtin_amdgcn_mfma_f32_16x16x32_bf16(af[fm], bb[fn],
                                                                          acc[fm][fn], 0, 0, 0);
        }
        __syncthreads();   // all reads of buf[cur] done; prefetch drained
    }

#pragma unroll
    for (int fm = 0; fm < FM; ++fm) {
#pragma unroll
        for (int fn = 0; fn < FN; ++fn) {
            int ng = n0 + wc * WN + fn * 16 + r;
            float bs = bias.p[ng >> 10][ng & 1023];
            int naddr = (ng >> 6) * chead + (ng & 63);
#pragma unroll
            for (int j = 0; j < 4; ++j) {
                int mg = m0 + wr * WM + fm * 16 + qd * 4 + j;   // C/D row = quad*4+reg
                int caddr = (mg & 1023) * crow + (mg >> 10) * cbatch + naddr;
                float v = acc[fm][fn][j] + bs;
                if (Rres) v += bf2f(Rres[caddr]);
                if (relu) v = fmaxf(v, 0.f);
                C[caddr] = f2bf(v);
            }
        }
    }
}

// ---------------------------------------------------------------------------
// V transpose: per (h,b) pair, (s,dk) 1024x64 -> (dk,s) 64x1024.
// src/dst base offset = hb*65536 (hb = h*2+b). grid (32 s-tiles, 32 hb).
// ---------------------------------------------------------------------------
__global__ __launch_bounds__(256) void vtrans(const u16* __restrict__ src,
                                              u16* __restrict__ dst)
{
    __shared__ u16 tl[32][68];   // stride 68 u16 = 34 dwords -> 2-way bank alias (free)
    const long boff = (long)blockIdx.y * 65536;
    const int s0 = blockIdx.x * 32;
    const int c = threadIdx.x & 63, r4 = threadIdx.x >> 6;
#pragma unroll
    for (int i = 0; i < 8; ++i)
        tl[r4 + 4 * i][c] = src[boff + (long)(s0 + r4 + 4 * i) * 64 + c];
    __syncthreads();
    const int cs = threadIdx.x & 31, rs = threadIdx.x >> 5;
#pragma unroll
    for (int i = 0; i < 8; ++i)
        dst[boff + (long)(rs + 8 * i) * 1024 + s0 + cs] = tl[cs][rs + 8 * i];
}

// ---------------------------------------------------------------------------
// Fused attention, wave-independent flash-style. One WAVE = 16 Q-rows of one
// (b,h), sweeping ALL keys. No LDS, no barriers.
// Q,K: (h,b,s,dk) bf16 at base h*131072 + b*65536. V: TRANSPOSED (h,b,dk,s).
//
// Swapped QK^T: s = mfma(K_frag, Q_frag) -> D: n=lane&15 = Q-row, m=qd*4+reg
// = key-in-tile. Each lane holds P for ONE Q-row, keys quad-local.
// PV contracts keys in the permuted order kpos(qd*8+j) = {tile 2c: qd*4+j}
// (j<4) / {tile 2c+1: qd*4+j-4} (j>=4); P and V use the same permutation, so
// the PV A-fragment is exactly the packed QK^T output (4 cvt_pk, no
// shuffles) and V^T fragments are two contiguous 8B loads.
// Max-free softmax: p = exp(min(s,60)) unnormalized (shift-invariant,
// clamped); row-sum = in-loop scalar + 2 shfl_xor; 1/sum folded into O.
// maskp: keys >= *maskp get p = 0 (covers padded tiles too).
//
// Grid: 512 flat, XCD-swizzled: bh = (bid&7) + 8*((bid>>3)&3) so all 16
// q-blocks of one (b,h) land on one XCD (4 bh x 256KB K/V = 1MB per L2).
// ---------------------------------------------------------------------------
__global__ __launch_bounds__(256) void attn_kernel(
    const u16* __restrict__ Q, const u16* __restrict__ K,
    const u16* __restrict__ V, u16* __restrict__ O,
    const int* __restrict__ maskp)
{
    const int tid = threadIdx.x;
    const int w = tid >> 6, lane = tid & 63;
    const int qd = lane >> 4, r = lane & 15;
    const int bid = blockIdx.x;
    const int xcd = bid & 7, slot = bid >> 3;
    const int bh = xcd + 8 * (slot & 3);     // 0..31
    const int qx = slot >> 2;                // 0..15
    const int b = bh >> 4, h = bh & 15;
    const long base = (long)h * 131072 + (long)b * 65536;
    const int qrow0 = qx * 64 + w * 16;

    int mi = maskp ? *maskp : 1024;
    mi = mi < 0 ? 0 : (mi > 1024 ? 1024 : mi);
    const int ntch = (mi + 31) >> 5;   // 32-key chunks

    // Q fragments (B operand: n=lane&15 = Q row, k=qd*8+j)
    bf16x8 aq0 = ld8(&Q[base + (qrow0 + r) * 64 + qd * 8]);
    bf16x8 aq1 = ld8(&Q[base + (qrow0 + r) * 64 + 32 + qd * 8]);

    f32x4 occ[4] = {};
    float sm = 0.f;
    const u16* kp = K + base + r * 64 + qd * 8;          // + t*1024
    const u16* vp = V + base + (long)r * 1024 + qd * 4;  // + c4*16384 + c*32 (+16)

    for (int c = 0; c < ntch; ++c) {
        const u16* kb = kp + c * 2048;
        f32x4 s0 = {}, s1 = {};
        s0 = __builtin_amdgcn_mfma_f32_16x16x32_bf16(ld8(kb),        aq0, s0, 0, 0, 0);
        s0 = __builtin_amdgcn_mfma_f32_16x16x32_bf16(ld8(kb + 32),   aq1, s0, 0, 0, 0);
        s1 = __builtin_amdgcn_mfma_f32_16x16x32_bf16(ld8(kb + 1024), aq0, s1, 0, 0, 0);
        s1 = __builtin_amdgcn_mfma_f32_16x16x32_bf16(ld8(kb + 1056), aq1, s1, 0, 0, 0);

        float p0[4], p1[4];
        const int kbase = c * 32 + qd * 4;
        if (kbase + 32 <= mi) {          // wave-uniform fast path: no mask checks
#pragma unroll
            for (int j = 0; j < 4; ++j) {
                p0[j] = __expf(fminf(s0[j] * 0.125f, 60.f));
                p1[j] = __expf(fminf(s1[j] * 0.125f, 60.f));
                sm += p0[j] + p1[j];
            }
        } else {
#pragma unroll
            for (int j = 0; j < 4; ++j) {
                p0[j] = (kbase + j < mi)      ? __expf(fminf(s0[j] * 0.125f, 60.f)) : 0.f;
                p1[j] = (kbase + 16 + j < mi) ? __expf(fminf(s1[j] * 0.125f, 60.f)) : 0.f;
                sm += p0[j] + p1[j];
            }
        }

        uint4 pk;
        pk.x = cvtpk(p0[0], p0[1]);
        pk.y = cvtpk(p0[2], p0[3]);
        pk.z = cvtpk(p1[0], p1[1]);
        pk.w = cvtpk(p1[2], p1[3]);
        bf16x8 pa = __builtin_bit_cast(bf16x8, pk);

#pragma unroll
        for (int c4 = 0; c4 < 4; ++c4) {
            const u16* vb = vp + c4 * 16384 + c * 32;
            uint2 lo = *(const uint2*)vb;
            uint2 hi = *(const uint2*)(vb + 16);
            uint4 vq = make_uint4(lo.x, lo.y, hi.x, hi.y);
            occ[c4] = __builtin_amdgcn_mfma_f32_16x16x32_bf16(
                pa, __builtin_bit_cast(bf16x8, vq), occ[c4], 0, 0, 0);
        }
    }

    // Row-sum total (lanes r, r+16, r+32, r+48 share Q-row r), then scale.
    sm += __shfl_xor(sm, 16);
    sm += __shfl_xor(sm, 32);
    float scale = 1.f / fmaxf(sm, 1e-30f);
    float scj[4];
#pragma unroll
    for (int j = 0; j < 4; ++j) scj[j] = __shfl(scale, qd * 4 + j);

    // occ[c4][j] = O[qrow0 + qd*4 + j][c4*16 + r]
#pragma unroll
    for (int c4 = 0; c4 < 4; ++c4)
#pragma unroll
        for (int j = 0; j < 4; ++j) {
            int row = qrow0 + qd * 4 + j;
            O[(long)(b * 1024 + row) * 1024 + h * 64 + c4 * 16 + r] =
                f2bf(occ[c4][j] * scj[j]);
        }
}

// ---------------------------------------------------------------------------
// BatchNorm1d over (B,S,D) with channel = s (S==D): stats over (b,d), biased
// var, eps=1e-5. One block per channel s. X bf16; writes bf16 to Y, or
// float32 to Yf if Yf != null (final layer). g/be float32. In-place safe.
// ---------------------------------------------------------------------------
__global__ __launch_bounds__(256) void bn_kernel(
    const u16* __restrict__ X, u16* __restrict__ Y, float* __restrict__ Yf,
    const float* __restrict__ g, const float* __restrict__ be)
{
    __shared__ float red[8];
    const int s = blockIdx.x, tid = threadIdx.x;
    const long b0 = (long)s * 1024, b1 = (long)(1024 + s) * 1024;
    uint2 a0 = *(const uint2*)&X[b0 + tid * 4];
    uint2 a1 = *(const uint2*)&X[b1 + tid * 4];
    float xs[8];
    xs[0] = bf2f((u16)a0.x); xs[1] = bf2f((u16)(a0.x >> 16));
    xs[2] = bf2f((u16)a0.y); xs[3] = bf2f((u16)(a0.y >> 16));
    xs[4] = bf2f((u16)a1.x); xs[5] = bf2f((u16)(a1.x >> 16));
    xs[6] = bf2f((u16)a1.y); xs[7] = bf2f((u16)(a1.y >> 16));
    float s1 = 0.f, s2 = 0.f;
#pragma unroll
    for (int j = 0; j < 8; ++j) { s1 += xs[j]; s2 += xs[j] * xs[j]; }
    for (int o = 32; o; o >>= 1) { s1 += __shfl_down(s1, o); s2 += __shfl_down(s2, o); }
    if ((tid & 63) == 0) { red[(tid >> 6) * 2] = s1; red[(tid >> 6) * 2 + 1] = s2; }
    __syncthreads();
    float S1 = red[0] + red[2] + red[4] + red[6];
    float S2 = red[1] + red[3] + red[5] + red[7];
    float mean = S1 * (1.f / 2048.f);
    float var = fmaxf(S2 * (1.f / 2048.f) - mean * mean, 0.f);
    float gs = g[s] * rsqrtf(var + 1e-5f);
    float bs = be[s];
    float y[8];
#pragma unroll
    for (int j = 0; j < 8; ++j) y[j] = (xs[j] - mean) * gs + bs;
    if (Yf) {
        *(float4*)&Yf[b0 + tid * 4] = make_float4(y[0], y[1], y[2], y[3]);
        *(float4*)&Yf[b1 + tid * 4] = make_float4(y[4], y[5], y[6], y[7]);
    } else {
        *(uint2*)&Y[b0 + tid * 4] = make_uint2(
            (u32)f2bf(y[0]) | ((u32)f2bf(y[1]) << 16),
            (u32)f2bf(y[2]) | ((u32)f2bf(y[3]) << 16));
        *(uint2*)&Y[b1 + tid * 4] = make_uint2(
            (u32)f2bf(y[4]) | ((u32)f2bf(y[5]) << 16),
            (u32)f2bf(y[6]) | ((u32)f2bf(y[7]) << 16));
    }
}

// ---------------------------------------------------------------------------
// One launch converts (f32 -> bf16) + transposes all 10 weight matrices of a
// layer into ws. s[0..5]: (16 heads)x(1024x64) QKV; s[6..7]: 1024x1024 Wo;
// s[8]: 1024x4096 W1; s[9]: 4096x1024 W2. 16384 blocks of 32x32 tiles.
// ---------------------------------------------------------------------------
struct TA { const float* s[10]; u16* d[10]; };

__global__ __launch_bounds__(256) void transpose_all(TA ta)
{
    __shared__ u16 tl[32][33];
    int id = blockIdx.x;
    const float* src; u16* dst; int Rr, Cc, tr, tc;
    if (id < 6144) {
        int wgt = id >> 10, rest = id & 1023;
        int head = rest >> 6, tile = rest & 63;
        tr = tile >> 1; tc = tile & 1; Rr = 1024; Cc = 64;
        src = ta.s[wgt] + head * 65536; dst = ta.d[wgt] + head * 65536;
    } else if (id < 8192) {
        int wgt = 6 + ((id - 6144) >> 10), rest = (id - 6144) & 1023;
        tr = rest >> 5; tc = rest & 31; Rr = 1024; Cc = 1024;
        src = ta.s[wgt]; dst = ta.d[wgt];
    } else if (id < 12288) {
        int rest = id - 8192;
        tr = rest >> 7; tc = rest & 127; Rr = 1024; Cc = 4096;
        src = ta.s[8]; dst = ta.d[8];
    } else {
        int rest = id - 12288;
        tr = rest >> 5; tc = rest & 31; Rr = 4096; Cc = 1024;
        src = ta.s[9]; dst = ta.d[9];
    }
    int r0 = tr * 32, c0 = tc * 32;
    int cl = threadIdx.x & 31, rl = threadIdx.x >> 5;
#pragma unroll
    for (int i = 0; i < 4; ++i)
        tl[rl + 8 * i][cl] = f2bf(src[(long)(r0 + rl + 8 * i) * Cc + c0 + cl]);
    __syncthreads();
#pragma unroll
    for (int i = 0; i < 4; ++i)
        dst[(long)(c0 + rl + 8 * i) * Rr + r0 + cl] = tl[cl][rl + 8 * i];
}

// ---------------------------------------------------------------------------
extern "C" void kernel_launch(void* const* d_in, const int* in_sizes, int n_in,
                              void* d_out, int out_size, void* d_ws, size_t ws_size,
                              hipStream_t stream)
{
    (void)in_sizes; (void)n_in; (void)out_size;
    const float* x   = (const float*)d_in[0];
    const float* Wq1 = (const float*)d_in[1];
    const float* bq1 = (const float*)d_in[2];
    const float* Wk1 = (const float*)d_in[3];
    const float* bk1 = (const float*)d_in[4];
    const float* Wv1 = (const float*)d_in[5];
    const float* bv1 = (const float*)d_in[6];
    const float* Wo1 = (const float*)d_in[7];
    const float* bo1 = (const float*)d_in[8];
    const float* Wq2 = (const float*)d_in[9];
    const float* bq2 = (const float*)d_in[10];
    const float* Wk2 = (const float*)d_in[11];
    const float* bk2 = (const float*)d_in[12];
    const float* Wv2 = (const float*)d_in[13];
    const float* bv2 = (const float*)d_in[14];
    const float* Wo2 = (const float*)d_in[15];
    const float* bo2 = (const float*)d_in[16];
    const float* g1  = (const float*)d_in[17];
    const float* be1 = (const float*)d_in[18];
    const float* g2  = (const float*)d_in[19];
    const float* be2 = (const float*)d_in[20];
    const float* g3  = (const float*)d_in[21];
    const float* be3 = (const float*)d_in[22];
    const float* W1  = (const float*)d_in[23];
    const float* bf1 = (const float*)d_in[24];
    const float* W2  = (const float*)d_in[25];
    const float* bf2 = (const float*)d_in[26];
    const int* maskp = (const int*)d_in[27];

    u16* ws = (u16*)d_ws;
    const size_t M1 = 1u << 20;
    u16* WT  = ws;             // 16M elems: transposed bf16 weights of current layer
    u16* QKV = ws + 16 * M1;   // 6M: fused QKV out, layout (h'=0..47, b, s, dk)
    u16* Vt  = ws + 22 * M1;   // 2M: V transposed (h, b, dk, s)
    u16* Ab  = ws + 24 * M1;   // 2M: attn out; reused as T2 in FFN
    u16* X1  = ws + 26 * M1;
    u16* Yb  = ws + 28 * M1;
    u16* Hb  = ws + 30 * M1;   // bf16 hidden state (layer input)
    u16* HID = ws + 32 * M1;   // 8M elems
    u16* T2  = Ab;             // FFN2 output (Ab dead by then)
    if (ws_size < (size_t)(40 * M1) * sizeof(u16)) return;  // fail loud (poisoned out)

    dim3 blk(256);
    dim3 g64(16, 32);     // O-proj / FFN2: 64x64 tiles, 512 blocks (2/CU)
    dim3 gqkv(48, 16);    // fused QKV: N=3072, 128x64 tiles (768 blocks, 3/CU)
    dim3 gF1(64, 16);     // FFN1: N=4096, 128x64 tiles (1024 blocks, 4/CU)
    dim3 gvt(32, 32);     // vtrans

    // x (f32) -> Hb (bf16)
    conv_f2b<<<dim3(2048), blk, 0, stream>>>(x, Hb);

    for (int l = 0; l < 4; ++l) {
        const u16* hin = Hb;

        TA ta;
        ta.s[0] = Wq1 + (size_t)l * M1;     ta.d[0] = WT + 0 * M1;
        ta.s[1] = Wk1 + (size_t)l * M1;     ta.d[1] = WT + 1 * M1;
        ta.s[2] = Wv1 + (size_t)l * M1;     ta.d[2] = WT + 2 * M1;
        ta.s[3] = Wq2 + (size_t)l * M1;     ta.d[3] = WT + 3 * M1;
        ta.s[4] = Wk2 + (size_t)l * M1;     ta.d[4] = WT + 4 * M1;
        ta.s[5] = Wv2 + (size_t)l * M1;     ta.d[5] = WT + 5 * M1;
        ta.s[6] = Wo1 + (size_t)l * M1;     ta.d[6] = WT + 6 * M1;
        ta.s[7] = Wo2 + (size_t)l * M1;     ta.d[7] = WT + 7 * M1;
        ta.s[8] = W1  + (size_t)l * 4 * M1; ta.d[8] = WT + 8 * M1;
        ta.s[9] = W2  + (size_t)l * 4 * M1; ta.d[9] = WT + 12 * M1;
        transpose_all<<<dim3(16384), blk, 0, stream>>>(ta);

        // ---- MHA1 (masked) ----
        B4 bQKV1 = {{bq1 + l * 1024, bk1 + l * 1024, bv1 + l * 1024, nullptr}};
        gemm_bt<128, 64><<<gqkv, blk, 0, stream>>>(hin, 1024, WT + 0 * M1, 1024, 65536,
            bQKV1, nullptr, QKV, 64, 65536, 131072, 1024, 0);
        vtrans<<<gvt, blk, 0, stream>>>(QKV + 4 * M1, Vt);
        attn_kernel<<<dim3(512), blk, 0, stream>>>(QKV, QKV + 2 * M1, Vt, Ab, maskp);
        B4 bO1 = {{bo1 + l * 1024, nullptr, nullptr, nullptr}};
        gemm_bt<64, 64><<<g64, blk, 0, stream>>>(Ab, 1024, WT + 6 * M1, 1024, 65536,
            bO1, hin, X1, 1024, 1048576, 64, 1024, 0);
        bn_kernel<<<dim3(1024), blk, 0, stream>>>(X1, X1, nullptr, g1 + l * 1024, be1 + l * 1024);

        // ---- MHA2 (unmasked, input x1, residual h) ----
        B4 bQKV2 = {{bq2 + l * 1024, bk2 + l * 1024, bv2 + l * 1024, nullptr}};
        gemm_bt<128, 64><<<gqkv, blk, 0, stream>>>(X1, 1024, WT + 3 * M1, 1024, 65536,
            bQKV2, nullptr, QKV, 64, 65536, 131072, 1024, 0);
        vtrans<<<gvt, blk, 0, stream>>>(QKV + 4 * M1, Vt);
        attn_kernel<<<dim3(512), blk, 0, stream>>>(QKV, QKV + 2 * M1, Vt, Ab, nullptr);
        B4 bO2 = {{bo2 + l * 1024, nullptr, nullptr, nullptr}};
        gemm_bt<64, 64><<<g64, blk, 0, stream>>>(Ab, 1024, WT + 7 * M1, 1024, 65536,
            bO2, hin, Yb, 1024, 1048576, 64, 1024, 0);
        bn_kernel<<<dim3(1024), blk, 0, stream>>>(Yb, Yb, nullptr, g2 + l * 1024, be2 + l * 1024);

        // ---- FFN (residual from x1) ----
        B4 bF1 = {{bf1 + l * 4096, bf1 + l * 4096 + 1024,
                   bf1 + l * 4096 + 2048, bf1 + l * 4096 + 3072}};
        gemm_bt<128, 64><<<gF1, blk, 0, stream>>>(Yb, 1024, WT + 8 * M1, 1024, 65536,
            bF1, nullptr, HID, 4096, 4194304, 64, 1024, 1);
        B4 bF2 = {{bf2 + l * 1024, nullptr, nullptr, nullptr}};
        gemm_bt<64, 64><<<g64, blk, 0, stream>>>(HID, 4096, WT + 12 * M1, 4096, 262144,
            bF2, X1, T2, 1024, 1048576, 64, 4096, 0);
        bn_kernel<<<dim3(1024), blk, 0, stream>>>(T2, Hb,
            (l == 3) ? (float*)d_out : nullptr, g3 + l * 1024, be3 + l * 1024);
    }
}

// Round 14
// 1141.846 us; speedup vs baseline: 1.3108x; 1.3108x over previous
//
#include <hip/hip_runtime.h>
#include <cstdint>
#include <cstddef>

typedef unsigned short u16;
typedef unsigned int u32;

typedef __bf16 bf16x8 __attribute__((ext_vector_type(8)));
typedef float f32x4 __attribute__((ext_vector_type(4)));

__device__ __forceinline__ float bf2f(u16 v) { return __builtin_bit_cast(float, (u32)v << 16); }
__device__ __forceinline__ u16 f2bf(float f) {
    u32 u = __builtin_bit_cast(u32, f);
    u += 0x7fffu + ((u >> 16) & 1u);   // RNE
    return (u16)(u >> 16);
}
__device__ __forceinline__ bf16x8 ld8(const u16* p) {
    return __builtin_bit_cast(bf16x8, *(const uint4*)p);
}
__device__ __forceinline__ u32 cvtpk(float lo, float hi) {
    u32 r;
    asm("v_cvt_pk_bf16_f32 %0, %1, %2" : "=v"(r) : "v"(lo), "v"(hi));
    return r;
}
__device__ __forceinline__ void glds16(const u16* g, u16* l) {
    __builtin_amdgcn_global_load_lds((const __attribute__((address_space(1))) void*)g,
                                     (__attribute__((address_space(3))) void*)l, 16, 0, 0);
}

// Bias selector: up to 4 pointer segments of 1024 floats each, indexed by n>>10.
struct B4 { const float* p[4]; };

// ---------------------------------------------------------------------------
// float32 -> bf16 elementwise convert (x -> Hb). n/1024 blocks of 256.
// ---------------------------------------------------------------------------
__global__ __launch_bounds__(256) void conv_f2b(const float* __restrict__ src,
                                                u16* __restrict__ dst)
{
    int idx = blockIdx.x * 256 + threadIdx.x;
    float4 v = ((const float4*)src)[idx];
    uint2 o;
    o.x = (u32)f2bf(v.x) | ((u32)f2bf(v.y) << 16);
    o.y = (u32)f2bf(v.z) | ((u32)f2bf(v.w) << 16);
    ((uint2*)dst)[idx] = o;
}

// ---------------------------------------------------------------------------
// GEMM: C = act( A[M,K] @ B[K,N] + bias[n] (+ R) ), A row-major bf16, B given
// TRANSPOSED bf16 (Bt element (n,k) at (n>>6)*nbs + (n&63)*ldb + k), bias via
// B4 segments (p[n>>10][n&1023], f32).
// C/R address: (m&1023)*crow + (m>>10)*cbatch + (n>>6)*chead + (n&63).
// M = gridDim.y*BM, N = gridDim.x*BN exactly; K multiple of 64.
//
// K-loop: BK=64, double-buffered LDS, prefetch-issue before compute (one
// barrier per K-tile; its vmcnt-drain lands after the compute phase, hiding
// the load latency). LDS layout XOR-swizzled (rule: linear glds dest +
// inverse-swizzled GLOBAL source col + swizzled ds_read addr):
//   staging lane l of a wave covers (row=l>>3, 16B-blk=l&7) holding global
//   col-blk (l&7)^(l>>3); fragment read of global blk X at row uses LDS blk
//   X^(row&7). 16 read lanes spread over 8 bank-groups = 2-way = free.
// ---------------------------------------------------------------------------
template <int BM, int BN>
__global__ __launch_bounds__(256) void gemm_bt(
    const u16* __restrict__ A, int lda,
    const u16* __restrict__ Bt, int ldb, int nbs,
    B4 bias,
    const u16* __restrict__ Rres,
    u16* __restrict__ C, int crow, int cbatch, int chead,
    int K, int relu)
{
    constexpr int WM = BM / 2, WN = BN / 2, FM = WM / 16, FN = WN / 16;
    __shared__ __align__(16) u16 Ald[2][BM * 64];
    __shared__ __align__(16) u16 Bld[2][BN * 64];
    const int tid = threadIdx.x;
    const int w = tid >> 6, lane = tid & 63;
    const int qd = lane >> 4, r = lane & 15;
    const int wr = w >> 1, wc = w & 1;
    const int m0 = blockIdx.y * BM, n0 = blockIdx.x * BN;
    // staging: one glds16 per wave covers 8 rows x 64 cols (16B per lane)
    const int srow = lane >> 3;                        // row within 8-row stripe
    const int scol = ((lane ^ (lane >> 3)) & 7) * 8;   // inverse-swizzled src col

    auto stage = [&](int buf, int k0) {
#pragma unroll
        for (int ii = 0; ii < BM / 32; ++ii) {
            int rbase = w * (BM / 4) + ii * 8;
            glds16(A + (long)(m0 + rbase + srow) * lda + k0 + scol,
                   &Ald[buf][rbase * 64]);
        }
#pragma unroll
        for (int ii = 0; ii < BN / 32; ++ii) {
            int nbase = w * (BN / 4) + ii * 8;
            int ng = n0 + nbase + srow;
            glds16(Bt + (long)(ng >> 6) * nbs + (long)(ng & 63) * ldb + k0 + scol,
                   &Bld[buf][nbase * 64]);
        }
    };

    f32x4 acc[FM][FN] = {};
    const int nt = K >> 6;

    stage(0, 0);
    __syncthreads();   // drains prologue stage (vmcnt) per barrier semantics

    for (int t = 0; t < nt; ++t) {
        const int cur = t & 1;
        if (t + 1 < nt) stage(cur ^ 1, (t + 1) << 6);   // prefetch next tile
#pragma unroll
        for (int s = 0; s < 2; ++s) {
            bf16x8 af[FM], bb[FN];
#pragma unroll
            for (int fm = 0; fm < FM; ++fm) {
                int row = wr * WM + fm * 16 + r;
                int blk = ((s << 2) | qd) ^ (r & 7);
                af[fm] = ld8(&Ald[cur][row * 64 + blk * 8]);
            }
#pragma unroll
            for (int fn = 0; fn < FN; ++fn) {
                int row = wc * WN + fn * 16 + r;
                int blk = ((s << 2) | qd) ^ (r & 7);
                bb[fn] = ld8(&Bld[cur][row * 64 + blk * 8]);
            }
#pragma unroll
            for (int fm = 0; fm < FM; ++fm)
#pragma unroll
                for (int fn = 0; fn < FN; ++fn)
                    acc[fm][fn] = __builtin_amdgcn_mfma_f32_16x16x32_bf16(af[fm], bb[fn],
                                                                          acc[fm][fn], 0, 0, 0);
        }
        __syncthreads();   // all reads of buf[cur] done; prefetch drained
    }

#pragma unroll
    for (int fm = 0; fm < FM; ++fm) {
#pragma unroll
        for (int fn = 0; fn < FN; ++fn) {
            int ng = n0 + wc * WN + fn * 16 + r;
            float bs = bias.p[ng >> 10][ng & 1023];
            int naddr = (ng >> 6) * chead + (ng & 63);
#pragma unroll
            for (int j = 0; j < 4; ++j) {
                int mg = m0 + wr * WM + fm * 16 + qd * 4 + j;   // C/D row = quad*4+reg
                int caddr = (mg & 1023) * crow + (mg >> 10) * cbatch + naddr;
                float v = acc[fm][fn][j] + bs;
                if (Rres) v += bf2f(Rres[caddr]);
                if (relu) v = fmaxf(v, 0.f);
                C[caddr] = f2bf(v);
            }
        }
    }
}

// ---------------------------------------------------------------------------
// V transpose: per (h,b) pair, (s,dk) 1024x64 -> (dk,s) 64x1024.
// src/dst base offset = hb*65536 (hb = h*2+b). grid (32 s-tiles, 32 hb).
// ---------------------------------------------------------------------------
__global__ __launch_bounds__(256) void vtrans(const u16* __restrict__ src,
                                              u16* __restrict__ dst)
{
    __shared__ u16 tl[32][68];   // stride 68 u16 = 34 dwords -> 2-way bank alias (free)
    const long boff = (long)blockIdx.y * 65536;
    const int s0 = blockIdx.x * 32;
    const int c = threadIdx.x & 63, r4 = threadIdx.x >> 6;
#pragma unroll
    for (int i = 0; i < 8; ++i)
        tl[r4 + 4 * i][c] = src[boff + (long)(s0 + r4 + 4 * i) * 64 + c];
    __syncthreads();
    const int cs = threadIdx.x & 31, rs = threadIdx.x >> 5;
#pragma unroll
    for (int i = 0; i < 8; ++i)
        dst[boff + (long)(rs + 8 * i) * 1024 + s0 + cs] = tl[cs][rs + 8 * i];
}

// ---------------------------------------------------------------------------
// Fused attention: block = 4 waves = 64 Q-rows of one (b,h); wave w owns 16
// rows. K and V^T chunks (32 keys) cooperatively staged in double-buffered
// LDS via glds16 (coalesced), XOR-swizzled per the GEMM recipe.
// Q,K: (h,b,s,dk) bf16 at base h*131072 + b*65536. V: TRANSPOSED (h,b,dk,s).
//
// Swapped QK^T: s = mfma(K_frag, Q_frag) -> lane (qd,r) holds P for Q-row
// qrow0+r. K rows are staged PERMUTED (LDS row rho <-> key kperm(rho)) so the
// lane's 8 P-values map to CONTIGUOUS keys qd*8..qd*8+7; the PV B-fragment is
// then one 16B LDS read of V^T[dk=c4*16+r][s-local qd*8..+7] (swizzled).
// Max-free softmax: p = exp(min(s,60)) unnormalized (shift-invariant,
// clamped); row-sum = in-loop scalar + 2 shfl_xor; 1/sum folded into O.
// maskp: keys >= *maskp get p = 0.
//
// Grid: 512 flat, XCD-swizzled: bh = (bid&7) + 8*((bid>>3)&3) so the 16
// q-blocks of one (b,h) land on one XCD (4 bh x 256KB K/V = 1MB per L2).
// ---------------------------------------------------------------------------
__global__ __launch_bounds__(256) void attn_kernel(
    const u16* __restrict__ Q, const u16* __restrict__ K,
    const u16* __restrict__ V, u16* __restrict__ O,
    const int* __restrict__ maskp)
{
    __shared__ __align__(16) u16 Kld[2][32 * 64];   // [key-local perm][dk]
    __shared__ __align__(16) u16 Vld[2][64 * 32];   // [dk][s-local]
    const int tid = threadIdx.x;
    const int w = tid >> 6, lane = tid & 63;
    const int qd = lane >> 4, r = lane & 15;
    const int bid = blockIdx.x;
    const int xcd = bid & 7, slot = bid >> 3;
    const int bh = xcd + 8 * (slot & 3);     // 0..31
    const int qx = slot >> 2;                // 0..15
    const int b = bh >> 4, h = bh & 15;
    const long base = (long)h * 131072 + (long)b * 65536;
    const int qrow0 = qx * 64 + w * 16;

    int mi = maskp ? *maskp : 1024;
    mi = mi < 0 ? 0 : (mi > 1024 ? 1024 : mi);
    const int ntch = (mi + 31) >> 5;   // 32-key chunks

    // --- staging indices (global src per-lane; LDS base wave-uniform) ---
    // K: LDS row rho holds global key kperm(rho); 16B dk-block d holds global
    //    dk-block d ^ (rho&7). kperm makes lane (qd,*)'s score keys contiguous:
    //    tile0 m=qd*4+j -> key qd*8+j ; tile1 -> key qd*8+4+j.
    const int krho  = tid >> 3;                                      // 0..31
    const int kperm = ((krho & 12) << 1) | ((krho & 16) >> 2) | (krho & 3);
    const int kg    = (tid & 7) ^ (krho & 7);
    // V: LDS row = dk (0..63), 16B s-block d holds global s-block d ^ F(row),
    //    F(row) = ((row&15) + ((row&15)>>2)) & 3 (spreads banks; see GEMM note)
    const int vrow = tid >> 2;                                       // 0..63
    const int vF   = ((vrow & 15) + ((vrow & 15) >> 2)) & 3;
    const int vg   = (tid & 3) ^ vF;

    auto stage = [&](int buf, int c) {
        glds16(K + base + (c * 32 + kperm) * 64 + kg * 8, &Kld[buf][w * 512]);
        glds16(V + base + (long)vrow * 1024 + c * 32 + vg * 8, &Vld[buf][w * 512]);
    };

    // Q fragments (B operand: n=lane&15 = Q row, k=qd*8+j)
    bf16x8 aq0 = ld8(&Q[base + (qrow0 + r) * 64 + qd * 8]);
    bf16x8 aq1 = ld8(&Q[base + (qrow0 + r) * 64 + 32 + qd * 8]);

    f32x4 occ[4] = {};
    float sm = 0.f;
    const int rx = r & 7;
    const int kb_a = (qd ^ rx) * 8;          // LDS blk of global dk-blk qd
    const int kb_b = ((4 + qd) ^ rx) * 8;    // LDS blk of global dk-blk 4+qd
    const int vblk = (qd ^ ((r + (r >> 2)) & 3)) * 8;   // LDS blk of s-blk qd

    if (ntch > 0) stage(0, 0);
    __syncthreads();

    for (int c = 0; c < ntch; ++c) {
        const int cur = c & 1;
        if (c + 1 < ntch) stage(cur ^ 1, c + 1);   // prefetch next chunk

        f32x4 s0 = {}, s1 = {};
        s0 = __builtin_amdgcn_mfma_f32_16x16x32_bf16(
                 ld8(&Kld[cur][r * 64 + kb_a]), aq0, s0, 0, 0, 0);
        s0 = __builtin_amdgcn_mfma_f32_16x16x32_bf16(
                 ld8(&Kld[cur][r * 64 + kb_b]), aq1, s0, 0, 0, 0);
        s1 = __builtin_amdgcn_mfma_f32_16x16x32_bf16(
                 ld8(&Kld[cur][(16 + r) * 64 + kb_a]), aq0, s1, 0, 0, 0);
        s1 = __builtin_amdgcn_mfma_f32_16x16x32_bf16(
                 ld8(&Kld[cur][(16 + r) * 64 + kb_b]), aq1, s1, 0, 0, 0);

        // s0[j] = P[Qrow][key c*32 + qd*8 + j]; s1[j] = ... + 4 + j
        float p0[4], p1[4];
        if ((c + 1) * 32 <= mi) {   // wave-uniform fast path
#pragma unroll
            for (int j = 0; j < 4; ++j) {
                p0[j] = __expf(fminf(s0[j] * 0.125f, 60.f));
                p1[j] = __expf(fminf(s1[j] * 0.125f, 60.f));
                sm += p0[j] + p1[j];
            }
        } else {
            const int kb8 = c * 32 + qd * 8;
#pragma unroll
            for (int j = 0; j < 4; ++j) {
                p0[j] = (kb8 + j < mi)     ? __expf(fminf(s0[j] * 0.125f, 60.f)) : 0.f;
                p1[j] = (kb8 + 4 + j < mi) ? __expf(fminf(s1[j] * 0.125f, 60.f)) : 0.f;
                sm += p0[j] + p1[j];
            }
        }

        uint4 pk;
        pk.x = cvtpk(p0[0], p0[1]);
        pk.y = cvtpk(p0[2], p0[3]);
        pk.z = cvtpk(p1[0], p1[1]);
        pk.w = cvtpk(p1[2], p1[3]);
        bf16x8 pa = __builtin_bit_cast(bf16x8, pk);   // keys qd*8 .. qd*8+7

#pragma unroll
        for (int c4 = 0; c4 < 4; ++c4) {
            bf16x8 vv = ld8(&Vld[cur][(c4 * 16 + r) * 32 + vblk]);
            occ[c4] = __builtin_amdgcn_mfma_f32_16x16x32_bf16(pa, vv, occ[c4], 0, 0, 0);
        }
        __syncthreads();   // all reads of buf[cur] done; prefetch drained
    }

    // Row-sum total (lanes r, r+16, r+32, r+48 share Q-row r), then scale.
    sm += __shfl_xor(sm, 16);
    sm += __shfl_xor(sm, 32);
    float scale = 1.f / fmaxf(sm, 1e-30f);
    float scj[4];
#pragma unroll
    for (int j = 0; j < 4; ++j) scj[j] = __shfl(scale, qd * 4 + j);

    // occ[c4][j] = O[qrow0 + qd*4 + j][c4*16 + r]
#pragma unroll
    for (int c4 = 0; c4 < 4; ++c4)
#pragma unroll
        for (int j = 0; j < 4; ++j) {
            int row = qrow0 + qd * 4 + j;
            O[(long)(b * 1024 + row) * 1024 + h * 64 + c4 * 16 + r] =
                f2bf(occ[c4][j] * scj[j]);
        }
}

// ---------------------------------------------------------------------------
// BatchNorm1d over (B,S,D) with channel = s (S==D): stats over (b,d), biased
// var, eps=1e-5. One block per channel s. X bf16; writes bf16 to Y, or
// float32 to Yf if Yf != null (final layer). g/be float32. In-place safe.
// ---------------------------------------------------------------------------
__global__ __launch_bounds__(256) void bn_kernel(
    const u16* __restrict__ X, u16* __restrict__ Y, float* __restrict__ Yf,
    const float* __restrict__ g, const float* __restrict__ be)
{
    __shared__ float red[8];
    const int s = blockIdx.x, tid = threadIdx.x;
    const long b0 = (long)s * 1024, b1 = (long)(1024 + s) * 1024;
    uint2 a0 = *(const uint2*)&X[b0 + tid * 4];
    uint2 a1 = *(const uint2*)&X[b1 + tid * 4];
    float xs[8];
    xs[0] = bf2f((u16)a0.x); xs[1] = bf2f((u16)(a0.x >> 16));
    xs[2] = bf2f((u16)a0.y); xs[3] = bf2f((u16)(a0.y >> 16));
    xs[4] = bf2f((u16)a1.x); xs[5] = bf2f((u16)(a1.x >> 16));
    xs[6] = bf2f((u16)a1.y); xs[7] = bf2f((u16)(a1.y >> 16));
    float s1 = 0.f, s2 = 0.f;
#pragma unroll
    for (int j = 0; j < 8; ++j) { s1 += xs[j]; s2 += xs[j] * xs[j]; }
    for (int o = 32; o; o >>= 1) { s1 += __shfl_down(s1, o); s2 += __shfl_down(s2, o); }
    if ((tid & 63) == 0) { red[(tid >> 6) * 2] = s1; red[(tid >> 6) * 2 + 1] = s2; }
    __syncthreads();
    float S1 = red[0] + red[2] + red[4] + red[6];
    float S2 = red[1] + red[3] + red[5] + red[7];
    float mean = S1 * (1.f / 2048.f);
    float var = fmaxf(S2 * (1.f / 2048.f) - mean * mean, 0.f);
    float gs = g[s] * rsqrtf(var + 1e-5f);
    float bs = be[s];
    float y[8];
#pragma unroll
    for (int j = 0; j < 8; ++j) y[j] = (xs[j] - mean) * gs + bs;
    if (Yf) {
        *(float4*)&Yf[b0 + tid * 4] = make_float4(y[0], y[1], y[2], y[3]);
        *(float4*)&Yf[b1 + tid * 4] = make_float4(y[4], y[5], y[6], y[7]);
    } else {
        *(uint2*)&Y[b0 + tid * 4] = make_uint2(
            (u32)f2bf(y[0]) | ((u32)f2bf(y[1]) << 16),
            (u32)f2bf(y[2]) | ((u32)f2bf(y[3]) << 16));
        *(uint2*)&Y[b1 + tid * 4] = make_uint2(
            (u32)f2bf(y[4]) | ((u32)f2bf(y[5]) << 16),
            (u32)f2bf(y[6]) | ((u32)f2bf(y[7]) << 16));
    }
}

// ---------------------------------------------------------------------------
// One launch converts (f32 -> bf16) + transposes all 10 weight matrices of a
// layer into ws. s[0..5]: (16 heads)x(1024x64) QKV; s[6..7]: 1024x1024 Wo;
// s[8]: 1024x4096 W1; s[9]: 4096x1024 W2. 16384 blocks of 32x32 tiles.
// ---------------------------------------------------------------------------
struct TA { const float* s[10]; u16* d[10]; };

__global__ __launch_bounds__(256) void transpose_all(TA ta)
{
    __shared__ u16 tl[32][33];
    int id = blockIdx.x;
    const float* src; u16* dst; int Rr, Cc, tr, tc;
    if (id < 6144) {
        int wgt = id >> 10, rest = id & 1023;
        int head = rest >> 6, tile = rest & 63;
        tr = tile >> 1; tc = tile & 1; Rr = 1024; Cc = 64;
        src = ta.s[wgt] + head * 65536; dst = ta.d[wgt] + head * 65536;
    } else if (id < 8192) {
        int wgt = 6 + ((id - 6144) >> 10), rest = (id - 6144) & 1023;
        tr = rest >> 5; tc = rest & 31; Rr = 1024; Cc = 1024;
        src = ta.s[wgt]; dst = ta.d[wgt];
    } else if (id < 12288) {
        int rest = id - 8192;
        tr = rest >> 7; tc = rest & 127; Rr = 1024; Cc = 4096;
        src = ta.s[8]; dst = ta.d[8];
    } else {
        int rest = id - 12288;
        tr = rest >> 5; tc = rest & 31; Rr = 4096; Cc = 1024;
        src = ta.s[9]; dst = ta.d[9];
    }
    int r0 = tr * 32, c0 = tc * 32;
    int cl = threadIdx.x & 31, rl = threadIdx.x >> 5;
#pragma unroll
    for (int i = 0; i < 4; ++i)
        tl[rl + 8 * i][cl] = f2bf(src[(long)(r0 + rl + 8 * i) * Cc + c0 + cl]);
    __syncthreads();
#pragma unroll
    for (int i = 0; i < 4; ++i)
        dst[(long)(c0 + rl + 8 * i) * Rr + r0 + cl] = tl[cl][rl + 8 * i];
}

// ---------------------------------------------------------------------------
extern "C" void kernel_launch(void* const* d_in, const int* in_sizes, int n_in,
                              void* d_out, int out_size, void* d_ws, size_t ws_size,
                              hipStream_t stream)
{
    (void)in_sizes; (void)n_in; (void)out_size;
    const float* x   = (const float*)d_in[0];
    const float* Wq1 = (const float*)d_in[1];
    const float* bq1 = (const float*)d_in[2];
    const float* Wk1 = (const float*)d_in[3];
    const float* bk1 = (const float*)d_in[4];
    const float* Wv1 = (const float*)d_in[5];
    const float* bv1 = (const float*)d_in[6];
    const float* Wo1 = (const float*)d_in[7];
    const float* bo1 = (const float*)d_in[8];
    const float* Wq2 = (const float*)d_in[9];
    const float* bq2 = (const float*)d_in[10];
    const float* Wk2 = (const float*)d_in[11];
    const float* bk2 = (const float*)d_in[12];
    const float* Wv2 = (const float*)d_in[13];
    const float* bv2 = (const float*)d_in[14];
    const float* Wo2 = (const float*)d_in[15];
    const float* bo2 = (const float*)d_in[16];
    const float* g1  = (const float*)d_in[17];
    const float* be1 = (const float*)d_in[18];
    const float* g2  = (const float*)d_in[19];
    const float* be2 = (const float*)d_in[20];
    const float* g3  = (const float*)d_in[21];
    const float* be3 = (const float*)d_in[22];
    const float* W1  = (const float*)d_in[23];
    const float* bf1 = (const float*)d_in[24];
    const float* W2  = (const float*)d_in[25];
    const float* bf2 = (const float*)d_in[26];
    const int* maskp = (const int*)d_in[27];

    u16* ws = (u16*)d_ws;
    const size_t M1 = 1u << 20;
    u16* WT  = ws;             // 16M elems: transposed bf16 weights of current layer
    u16* QKV = ws + 16 * M1;   // 6M: fused QKV out, layout (h'=0..47, b, s, dk)
    u16* Vt  = ws + 22 * M1;   // 2M: V transposed (h, b, dk, s)
    u16* Ab  = ws + 24 * M1;   // 2M: attn out; reused as T2 in FFN
    u16* X1  = ws + 26 * M1;
    u16* Yb  = ws + 28 * M1;
    u16* Hb  = ws + 30 * M1;   // bf16 hidden state (layer input)
    u16* HID = ws + 32 * M1;   // 8M elems
    u16* T2  = Ab;             // FFN2 output (Ab dead by then)
    if (ws_size < (size_t)(40 * M1) * sizeof(u16)) return;  // fail loud (poisoned out)

    dim3 blk(256);
    dim3 g64(16, 32);     // O-proj / FFN2: 64x64 tiles, 512 blocks (2/CU)
    dim3 gqkv(48, 16);    // fused QKV: N=3072, 128x64 tiles (768 blocks, 3/CU)
    dim3 gF1(64, 16);     // FFN1: N=4096, 128x64 tiles (1024 blocks, 4/CU)
    dim3 gvt(32, 32);     // vtrans

    // x (f32) -> Hb (bf16)
    conv_f2b<<<dim3(2048), blk, 0, stream>>>(x, Hb);

    for (int l = 0; l < 4; ++l) {
        const u16* hin = Hb;

        TA ta;
        ta.s[0] = Wq1 + (size_t)l * M1;     ta.d[0] = WT + 0 * M1;
        ta.s[1] = Wk1 + (size_t)l * M1;     ta.d[1] = WT + 1 * M1;
        ta.s[2] = Wv1 + (size_t)l * M1;     ta.d[2] = WT + 2 * M1;
        ta.s[3] = Wq2 + (size_t)l * M1;     ta.d[3] = WT + 3 * M1;
        ta.s[4] = Wk2 + (size_t)l * M1;     ta.d[4] = WT + 4 * M1;
        ta.s[5] = Wv2 + (size_t)l * M1;     ta.d[5] = WT + 5 * M1;
        ta.s[6] = Wo1 + (size_t)l * M1;     ta.d[6] = WT + 6 * M1;
        ta.s[7] = Wo2 + (size_t)l * M1;     ta.d[7] = WT + 7 * M1;
        ta.s[8] = W1  + (size_t)l * 4 * M1; ta.d[8] = WT + 8 * M1;
        ta.s[9] = W2  + (size_t)l * 4 * M1; ta.d[9] = WT + 12 * M1;
        transpose_all<<<dim3(16384), blk, 0, stream>>>(ta);

        // ---- MHA1 (masked) ----
        B4 bQKV1 = {{bq1 + l * 1024, bk1 + l * 1024, bv1 + l * 1024, nullptr}};
        gemm_bt<128, 64><<<gqkv, blk, 0, stream>>>(hin, 1024, WT + 0 * M1, 1024, 65536,
            bQKV1, nullptr, QKV, 64, 65536, 131072, 1024, 0);
        vtrans<<<gvt, blk, 0, stream>>>(QKV + 4 * M1, Vt);
        attn_kernel<<<dim3(512), blk, 0, stream>>>(QKV, QKV + 2 * M1, Vt, Ab, maskp);
        B4 bO1 = {{bo1 + l * 1024, nullptr, nullptr, nullptr}};
        gemm_bt<64, 64><<<g64, blk, 0, stream>>>(Ab, 1024, WT + 6 * M1, 1024, 65536,
            bO1, hin, X1, 1024, 1048576, 64, 1024, 0);
        bn_kernel<<<dim3(1024), blk, 0, stream>>>(X1, X1, nullptr, g1 + l * 1024, be1 + l * 1024);

        // ---- MHA2 (unmasked, input x1, residual h) ----
        B4 bQKV2 = {{bq2 + l * 1024, bk2 + l * 1024, bv2 + l * 1024, nullptr}};
        gemm_bt<128, 64><<<gqkv, blk, 0, stream>>>(X1, 1024, WT + 3 * M1, 1024, 65536,
            bQKV2, nullptr, QKV, 64, 65536, 131072, 1024, 0);
        vtrans<<<gvt, blk, 0, stream>>>(QKV + 4 * M1, Vt);
        attn_kernel<<<dim3(512), blk, 0, stream>>>(QKV, QKV + 2 * M1, Vt, Ab, nullptr);
        B4 bO2 = {{bo2 + l * 1024, nullptr, nullptr, nullptr}};
        gemm_bt<64, 64><<<g64, blk, 0, stream>>>(Ab, 1024, WT + 7 * M1, 1024, 65536,
            bO2, hin, Yb, 1024, 1048576, 64, 1024, 0);
        bn_kernel<<<dim3(1024), blk, 0, stream>>>(Yb, Yb, nullptr, g2 + l * 1024, be2 + l * 1024);

        // ---- FFN (residual from x1) ----
        B4 bF1 = {{bf1 + l * 4096, bf1 + l * 4096 + 1024,
                   bf1 + l * 4096 + 2048, bf1 + l * 4096 + 3072}};
        gemm_bt<128, 64><<<gF1, blk, 0, stream>>>(Yb, 1024, WT + 8 * M1, 1024, 65536,
            bF1, nullptr, HID, 4096, 4194304, 64, 1024, 1);
        B4 bF2 = {{bf2 + l * 1024, nullptr, nullptr, nullptr}};
        gemm_bt<64, 64><<<g64, blk, 0, stream>>>(HID, 4096, WT + 12 * M1, 4096, 262144,
            bF2, X1, T2, 1024, 1048576, 64, 4096, 0);
        bn_kernel<<<dim3(1024), blk, 0, stream>>>(T2, Hb,
            (l == 3) ? (float*)d_out : nullptr, g3 + l * 1024, be3 + l * 1024);
    }
}

// Round 15
// 1131.741 us; speedup vs baseline: 1.3225x; 1.0089x over previous
//
#include <hip/hip_runtime.h>
#include <cstdint>
#include <cstddef>

typedef unsigned short u16;
typedef unsigned int u32;

typedef __bf16 bf16x8 __attribute__((ext_vector_type(8)));
typedef float f32x4 __attribute__((ext_vector_type(4)));

__device__ __forceinline__ float bf2f(u16 v) { return __builtin_bit_cast(float, (u32)v << 16); }
__device__ __forceinline__ u16 f2bf(float f) {
    u32 u = __builtin_bit_cast(u32, f);
    u += 0x7fffu + ((u >> 16) & 1u);   // RNE
    return (u16)(u >> 16);
}
__device__ __forceinline__ bf16x8 ld8(const u16* p) {
    return __builtin_bit_cast(bf16x8, *(const uint4*)p);
}
__device__ __forceinline__ u32 cvtpk(float lo, float hi) {
    u32 r;
    asm("v_cvt_pk_bf16_f32 %0, %1, %2" : "=v"(r) : "v"(lo), "v"(hi));
    return r;
}
__device__ __forceinline__ void glds16(const u16* g, u16* l) {
    __builtin_amdgcn_global_load_lds((const __attribute__((address_space(1))) void*)g,
                                     (__attribute__((address_space(3))) void*)l, 16, 0, 0);
}

// Bias selector: up to 4 pointer segments of 1024 floats each, indexed by n>>10.
struct B4 { const float* p[4]; };
// Split-K partial buffers (f32), one per K-slice.
struct P4 { float* p[4]; };

// ---------------------------------------------------------------------------
// float32 -> bf16 elementwise convert (x -> Hb). n/1024 blocks of 256.
// ---------------------------------------------------------------------------
__global__ __launch_bounds__(256) void conv_f2b(const float* __restrict__ src,
                                                u16* __restrict__ dst)
{
    int idx = blockIdx.x * 256 + threadIdx.x;
    float4 v = ((const float4*)src)[idx];
    uint2 o;
    o.x = (u32)f2bf(v.x) | ((u32)f2bf(v.y) << 16);
    o.y = (u32)f2bf(v.z) | ((u32)f2bf(v.w) << 16);
    ((uint2*)dst)[idx] = o;
}

// ---------------------------------------------------------------------------
// GEMM: C = act( A[M,K] @ B[K,N] + bias[n] (+ R) ), A row-major bf16, B given
// TRANSPOSED bf16 (Bt element (n,k) at (n>>6)*nbs + (n&63)*ldb + k), bias via
// B4 segments (p[n>>10][n&1023], f32).
// C/R address: (m&1023)*crow + (m>>10)*cbatch + (n>>6)*chead + (n&63).
// M = gridDim.y*BM, N = gridDim.x*BN exactly; K multiple of 64.
//
// K-loop: BK=64, double-buffered LDS, prefetch-issue before compute (one
// barrier per K-tile). LDS layout XOR-swizzled (linear glds dest +
// inverse-swizzled GLOBAL source col + swizzled ds_read addr).
// ---------------------------------------------------------------------------
template <int BM, int BN>
__global__ __launch_bounds__(256) void gemm_bt(
    const u16* __restrict__ A, int lda,
    const u16* __restrict__ Bt, int ldb, int nbs,
    B4 bias,
    const u16* __restrict__ Rres,
    u16* __restrict__ C, int crow, int cbatch, int chead,
    int K, int relu)
{
    constexpr int WM = BM / 2, WN = BN / 2, FM = WM / 16, FN = WN / 16;
    __shared__ __align__(16) u16 Ald[2][BM * 64];
    __shared__ __align__(16) u16 Bld[2][BN * 64];
    const int tid = threadIdx.x;
    const int w = tid >> 6, lane = tid & 63;
    const int qd = lane >> 4, r = lane & 15;
    const int wr = w >> 1, wc = w & 1;
    const int m0 = blockIdx.y * BM, n0 = blockIdx.x * BN;
    const int srow = lane >> 3;                        // row within 8-row stripe
    const int scol = ((lane ^ (lane >> 3)) & 7) * 8;   // inverse-swizzled src col

    auto stage = [&](int buf, int k0) {
#pragma unroll
        for (int ii = 0; ii < BM / 32; ++ii) {
            int rbase = w * (BM / 4) + ii * 8;
            glds16(A + (long)(m0 + rbase + srow) * lda + k0 + scol,
                   &Ald[buf][rbase * 64]);
        }
#pragma unroll
        for (int ii = 0; ii < BN / 32; ++ii) {
            int nbase = w * (BN / 4) + ii * 8;
            int ng = n0 + nbase + srow;
            glds16(Bt + (long)(ng >> 6) * nbs + (long)(ng & 63) * ldb + k0 + scol,
                   &Bld[buf][nbase * 64]);
        }
    };

    f32x4 acc[FM][FN] = {};
    const int nt = K >> 6;

    stage(0, 0);
    __syncthreads();   // drains prologue stage (vmcnt) per barrier semantics

    for (int t = 0; t < nt; ++t) {
        const int cur = t & 1;
        if (t + 1 < nt) stage(cur ^ 1, (t + 1) << 6);   // prefetch next tile
#pragma unroll
        for (int s = 0; s < 2; ++s) {
            bf16x8 af[FM], bb[FN];
#pragma unroll
            for (int fm = 0; fm < FM; ++fm) {
                int row = wr * WM + fm * 16 + r;
                int blk = ((s << 2) | qd) ^ (r & 7);
                af[fm] = ld8(&Ald[cur][row * 64 + blk * 8]);
            }
#pragma unroll
            for (int fn = 0; fn < FN; ++fn) {
                int row = wc * WN + fn * 16 + r;
                int blk = ((s << 2) | qd) ^ (r & 7);
                bb[fn] = ld8(&Bld[cur][row * 64 + blk * 8]);
            }
#pragma unroll
            for (int fm = 0; fm < FM; ++fm)
#pragma unroll
                for (int fn = 0; fn < FN; ++fn)
                    acc[fm][fn] = __builtin_amdgcn_mfma_f32_16x16x32_bf16(af[fm], bb[fn],
                                                                          acc[fm][fn], 0, 0, 0);
        }
        __syncthreads();   // all reads of buf[cur] done; prefetch drained
    }

#pragma unroll
    for (int fm = 0; fm < FM; ++fm) {
#pragma unroll
        for (int fn = 0; fn < FN; ++fn) {
            int ng = n0 + wc * WN + fn * 16 + r;
            float bs = bias.p[ng >> 10][ng & 1023];
            int naddr = (ng >> 6) * chead + (ng & 63);
#pragma unroll
            for (int j = 0; j < 4; ++j) {
                int mg = m0 + wr * WM + fm * 16 + qd * 4 + j;   // C/D row = quad*4+reg
                int caddr = (mg & 1023) * crow + (mg >> 10) * cbatch + naddr;
                float v = acc[fm][fn][j] + bs;
                if (Rres) v += bf2f(Rres[caddr]);
                if (relu) v = fmaxf(v, 0.f);
                C[caddr] = f2bf(v);
            }
        }
    }
}

// ---------------------------------------------------------------------------
// Split-K GEMM (FFN2): 64x64 tile, K-slice = blockIdx.z (1024 wide). Same
// verified loop body as gemm_bt; epilogue writes RAW f32 partials to
// part.p[z] at (m&1023)*1024 + (m>>10)*1048576 + n. No bias/resid/act.
// Grid (16, 32, 4) = 2048 blocks -> ~5 blocks/CU (LDS-capped), 2.5x the
// residency of the single-slice version; bn_merge reduces the 4 slices.
// ---------------------------------------------------------------------------
__global__ __launch_bounds__(256) void gemm_splitk(
    const u16* __restrict__ A, int lda,
    const u16* __restrict__ Bt, int ldb, int nbs,
    P4 part)
{
    constexpr int BM = 64, BN = 64, WM = 32, WN = 32, FM = 2, FN = 2;
    __shared__ __align__(16) u16 Ald[2][BM * 64];
    __shared__ __align__(16) u16 Bld[2][BN * 64];
    const int tid = threadIdx.x;
    const int w = tid >> 6, lane = tid & 63;
    const int qd = lane >> 4, r = lane & 15;
    const int wr = w >> 1, wc = w & 1;
    const int m0 = blockIdx.y * BM, n0 = blockIdx.x * BN;
    const int kbeg = blockIdx.z << 10;   // K-slice base (1024 per slice)
    float* __restrict__ C = part.p[blockIdx.z];
    const int srow = lane >> 3;
    const int scol = ((lane ^ (lane >> 3)) & 7) * 8;

    auto stage = [&](int buf, int k0) {
#pragma unroll
        for (int ii = 0; ii < 2; ++ii) {
            int rbase = w * 16 + ii * 8;
            glds16(A + (long)(m0 + rbase + srow) * lda + k0 + scol,
                   &Ald[buf][rbase * 64]);
        }
#pragma unroll
        for (int ii = 0; ii < 2; ++ii) {
            int nbase = w * 16 + ii * 8;
            int ng = n0 + nbase + srow;
            glds16(Bt + (long)(ng >> 6) * nbs + (long)(ng & 63) * ldb + k0 + scol,
                   &Bld[buf][nbase * 64]);
        }
    };

    f32x4 acc[FM][FN] = {};

    stage(0, kbeg);
    __syncthreads();

    for (int t = 0; t < 16; ++t) {
        const int cur = t & 1;
        if (t + 1 < 16) stage(cur ^ 1, kbeg + ((t + 1) << 6));
#pragma unroll
        for (int s = 0; s < 2; ++s) {
            bf16x8 af[FM], bb[FN];
#pragma unroll
            for (int fm = 0; fm < FM; ++fm) {
                int row = wr * WM + fm * 16 + r;
                int blk = ((s << 2) | qd) ^ (r & 7);
                af[fm] = ld8(&Ald[cur][row * 64 + blk * 8]);
            }
#pragma unroll
            for (int fn = 0; fn < FN; ++fn) {
                int row = wc * WN + fn * 16 + r;
                int blk = ((s << 2) | qd) ^ (r & 7);
                bb[fn] = ld8(&Bld[cur][row * 64 + blk * 8]);
            }
#pragma unroll
            for (int fm = 0; fm < FM; ++fm)
#pragma unroll
                for (int fn = 0; fn < FN; ++fn)
                    acc[fm][fn] = __builtin_amdgcn_mfma_f32_16x16x32_bf16(af[fm], bb[fn],
                                                                          acc[fm][fn], 0, 0, 0);
        }
        __syncthreads();
    }

#pragma unroll
    for (int fm = 0; fm < FM; ++fm) {
#pragma unroll
        for (int fn = 0; fn < FN; ++fn) {
            int ng = n0 + wc * WN + fn * 16 + r;
#pragma unroll
            for (int j = 0; j < 4; ++j) {
                int mg = m0 + wr * WM + fm * 16 + qd * 4 + j;
                C[(mg & 1023) * 1024 + (mg >> 10) * 1048576 + ng] = acc[fm][fn][j];
            }
        }
    }
}

// ---------------------------------------------------------------------------
// bn_merge: sums 4 split-K partials + bias[n] + residual (bf16), then applies
// BatchNorm (channel = s, stats over (b,d), biased var, eps=1e-5) and writes
// bf16 Y or f32 Yf. One block per channel s; same reduction as bn_kernel.
// ---------------------------------------------------------------------------
__global__ __launch_bounds__(256) void bn_merge(
    P4 part, const float* __restrict__ bias, const u16* __restrict__ resid,
    u16* __restrict__ Y, float* __restrict__ Yf,
    const float* __restrict__ g, const float* __restrict__ be)
{
    __shared__ float red[8];
    const int s = blockIdx.x, tid = threadIdx.x;
    const int n0 = tid * 4;
    float xs[8];
#pragma unroll
    for (int b = 0; b < 2; ++b) {
        long off = (long)b * 1048576 + s * 1024 + n0;
        float4 v0 = *(const float4*)&part.p[0][off];
        float4 v1 = *(const float4*)&part.p[1][off];
        float4 v2 = *(const float4*)&part.p[2][off];
        float4 v3 = *(const float4*)&part.p[3][off];
        float4 bv = *(const float4*)&bias[n0];
        uint2 rr = *(const uint2*)&resid[off];
        xs[b * 4 + 0] = v0.x + v1.x + v2.x + v3.x + bv.x + bf2f((u16)rr.x);
        xs[b * 4 + 1] = v0.y + v1.y + v2.y + v3.y + bv.y + bf2f((u16)(rr.x >> 16));
        xs[b * 4 + 2] = v0.z + v1.z + v2.z + v3.z + bv.z + bf2f((u16)rr.y);
        xs[b * 4 + 3] = v0.w + v1.w + v2.w + v3.w + bv.w + bf2f((u16)(rr.y >> 16));
    }
    float s1 = 0.f, s2 = 0.f;
#pragma unroll
    for (int j = 0; j < 8; ++j) { s1 += xs[j]; s2 += xs[j] * xs[j]; }
    for (int o = 32; o; o >>= 1) { s1 += __shfl_down(s1, o); s2 += __shfl_down(s2, o); }
    if ((tid & 63) == 0) { red[(tid >> 6) * 2] = s1; red[(tid >> 6) * 2 + 1] = s2; }
    __syncthreads();
    float S1 = red[0] + red[2] + red[4] + red[6];
    float S2 = red[1] + red[3] + red[5] + red[7];
    float mean = S1 * (1.f / 2048.f);
    float var = fmaxf(S2 * (1.f / 2048.f) - mean * mean, 0.f);
    float gs = g[s] * rsqrtf(var + 1e-5f);
    float bs = be[s];
    float y[8];
#pragma unroll
    for (int j = 0; j < 8; ++j) y[j] = (xs[j] - mean) * gs + bs;
#pragma unroll
    for (int b = 0; b < 2; ++b) {
        long off = (long)b * 1048576 + s * 1024 + n0;
        if (Yf) {
            *(float4*)&Yf[off] = make_float4(y[b * 4], y[b * 4 + 1], y[b * 4 + 2], y[b * 4 + 3]);
        } else {
            *(uint2*)&Y[off] = make_uint2(
                (u32)f2bf(y[b * 4 + 0]) | ((u32)f2bf(y[b * 4 + 1]) << 16),
                (u32)f2bf(y[b * 4 + 2]) | ((u32)f2bf(y[b * 4 + 3]) << 16));
        }
    }
}

// ---------------------------------------------------------------------------
// V transpose: per (h,b) pair, (s,dk) 1024x64 -> (dk,s) 64x1024.
// src/dst base offset = hb*65536 (hb = h*2+b). grid (32 s-tiles, 32 hb).
// ---------------------------------------------------------------------------
__global__ __launch_bounds__(256) void vtrans(const u16* __restrict__ src,
                                              u16* __restrict__ dst)
{
    __shared__ u16 tl[32][68];   // stride 68 u16 = 34 dwords -> 2-way bank alias (free)
    const long boff = (long)blockIdx.y * 65536;
    const int s0 = blockIdx.x * 32;
    const int c = threadIdx.x & 63, r4 = threadIdx.x >> 6;
#pragma unroll
    for (int i = 0; i < 8; ++i)
        tl[r4 + 4 * i][c] = src[boff + (long)(s0 + r4 + 4 * i) * 64 + c];
    __syncthreads();
    const int cs = threadIdx.x & 31, rs = threadIdx.x >> 5;
#pragma unroll
    for (int i = 0; i < 8; ++i)
        dst[boff + (long)(rs + 8 * i) * 1024 + s0 + cs] = tl[cs][rs + 8 * i];
}

// ---------------------------------------------------------------------------
// Fused attention: block = 4 waves = 64 Q-rows of one (b,h); wave w owns 16
// rows. K and V^T chunks (32 keys) cooperatively staged in double-buffered
// LDS via glds16 (coalesced), XOR-swizzled per the GEMM recipe.
// Q,K: (h,b,s,dk) bf16 at base h*131072 + b*65536. V: TRANSPOSED (h,b,dk,s).
// Swapped QK^T + kperm staging; max-free softmax; 1/sum folded into O.
// VERIFIED round 14: attn dropped out of top-5 (was 89.7 us).
// ---------------------------------------------------------------------------
__global__ __launch_bounds__(256) void attn_kernel(
    const u16* __restrict__ Q, const u16* __restrict__ K,
    const u16* __restrict__ V, u16* __restrict__ O,
    const int* __restrict__ maskp)
{
    __shared__ __align__(16) u16 Kld[2][32 * 64];   // [key-local perm][dk]
    __shared__ __align__(16) u16 Vld[2][64 * 32];   // [dk][s-local]
    const int tid = threadIdx.x;
    const int w = tid >> 6, lane = tid & 63;
    const int qd = lane >> 4, r = lane & 15;
    const int bid = blockIdx.x;
    const int xcd = bid & 7, slot = bid >> 3;
    const int bh = xcd + 8 * (slot & 3);     // 0..31
    const int qx = slot >> 2;                // 0..15
    const int b = bh >> 4, h = bh & 15;
    const long base = (long)h * 131072 + (long)b * 65536;
    const int qrow0 = qx * 64 + w * 16;

    int mi = maskp ? *maskp : 1024;
    mi = mi < 0 ? 0 : (mi > 1024 ? 1024 : mi);
    const int ntch = (mi + 31) >> 5;   // 32-key chunks

    const int krho  = tid >> 3;                                      // 0..31
    const int kperm = ((krho & 12) << 1) | ((krho & 16) >> 2) | (krho & 3);
    const int kg    = (tid & 7) ^ (krho & 7);
    const int vrow = tid >> 2;                                       // 0..63
    const int vF   = ((vrow & 15) + ((vrow & 15) >> 2)) & 3;
    const int vg   = (tid & 3) ^ vF;

    auto stage = [&](int buf, int c) {
        glds16(K + base + (c * 32 + kperm) * 64 + kg * 8, &Kld[buf][w * 512]);
        glds16(V + base + (long)vrow * 1024 + c * 32 + vg * 8, &Vld[buf][w * 512]);
    };

    bf16x8 aq0 = ld8(&Q[base + (qrow0 + r) * 64 + qd * 8]);
    bf16x8 aq1 = ld8(&Q[base + (qrow0 + r) * 64 + 32 + qd * 8]);

    f32x4 occ[4] = {};
    float sm = 0.f;
    const int rx = r & 7;
    const int kb_a = (qd ^ rx) * 8;
    const int kb_b = ((4 + qd) ^ rx) * 8;
    const int vblk = (qd ^ ((r + (r >> 2)) & 3)) * 8;

    if (ntch > 0) stage(0, 0);
    __syncthreads();

    for (int c = 0; c < ntch; ++c) {
        const int cur = c & 1;
        if (c + 1 < ntch) stage(cur ^ 1, c + 1);

        f32x4 s0 = {}, s1 = {};
        s0 = __builtin_amdgcn_mfma_f32_16x16x32_bf16(
                 ld8(&Kld[cur][r * 64 + kb_a]), aq0, s0, 0, 0, 0);
        s0 = __builtin_amdgcn_mfma_f32_16x16x32_bf16(
                 ld8(&Kld[cur][r * 64 + kb_b]), aq1, s0, 0, 0, 0);
        s1 = __builtin_amdgcn_mfma_f32_16x16x32_bf16(
                 ld8(&Kld[cur][(16 + r) * 64 + kb_a]), aq0, s1, 0, 0, 0);
        s1 = __builtin_amdgcn_mfma_f32_16x16x32_bf16(
                 ld8(&Kld[cur][(16 + r) * 64 + kb_b]), aq1, s1, 0, 0, 0);

        float p0[4], p1[4];
        if ((c + 1) * 32 <= mi) {
#pragma unroll
            for (int j = 0; j < 4; ++j) {
                p0[j] = __expf(fminf(s0[j] * 0.125f, 60.f));
                p1[j] = __expf(fminf(s1[j] * 0.125f, 60.f));
                sm += p0[j] + p1[j];
            }
        } else {
            const int kb8 = c * 32 + qd * 8;
#pragma unroll
            for (int j = 0; j < 4; ++j) {
                p0[j] = (kb8 + j < mi)     ? __expf(fminf(s0[j] * 0.125f, 60.f)) : 0.f;
                p1[j] = (kb8 + 4 + j < mi) ? __expf(fminf(s1[j] * 0.125f, 60.f)) : 0.f;
                sm += p0[j] + p1[j];
            }
        }

        uint4 pk;
        pk.x = cvtpk(p0[0], p0[1]);
        pk.y = cvtpk(p0[2], p0[3]);
        pk.z = cvtpk(p1[0], p1[1]);
        pk.w = cvtpk(p1[2], p1[3]);
        bf16x8 pa = __builtin_bit_cast(bf16x8, pk);

#pragma unroll
        for (int c4 = 0; c4 < 4; ++c4) {
            bf16x8 vv = ld8(&Vld[cur][(c4 * 16 + r) * 32 + vblk]);
            occ[c4] = __builtin_amdgcn_mfma_f32_16x16x32_bf16(pa, vv, occ[c4], 0, 0, 0);
        }
        __syncthreads();
    }

    sm += __shfl_xor(sm, 16);
    sm += __shfl_xor(sm, 32);
    float scale = 1.f / fmaxf(sm, 1e-30f);
    float scj[4];
#pragma unroll
    for (int j = 0; j < 4; ++j) scj[j] = __shfl(scale, qd * 4 + j);

#pragma unroll
    for (int c4 = 0; c4 < 4; ++c4)
#pragma unroll
        for (int j = 0; j < 4; ++j) {
            int row = qrow0 + qd * 4 + j;
            O[(long)(b * 1024 + row) * 1024 + h * 64 + c4 * 16 + r] =
                f2bf(occ[c4][j] * scj[j]);
        }
}

// ---------------------------------------------------------------------------
// BatchNorm1d over (B,S,D) with channel = s (S==D): stats over (b,d), biased
// var, eps=1e-5. One block per channel s. X bf16; writes bf16 to Y, or
// float32 to Yf if Yf != null (final layer). g/be float32. In-place safe.
// ---------------------------------------------------------------------------
__global__ __launch_bounds__(256) void bn_kernel(
    const u16* __restrict__ X, u16* __restrict__ Y, float* __restrict__ Yf,
    const float* __restrict__ g, const float* __restrict__ be)
{
    __shared__ float red[8];
    const int s = blockIdx.x, tid = threadIdx.x;
    const long b0 = (long)s * 1024, b1 = (long)(1024 + s) * 1024;
    uint2 a0 = *(const uint2*)&X[b0 + tid * 4];
    uint2 a1 = *(const uint2*)&X[b1 + tid * 4];
    float xs[8];
    xs[0] = bf2f((u16)a0.x); xs[1] = bf2f((u16)(a0.x >> 16));
    xs[2] = bf2f((u16)a0.y); xs[3] = bf2f((u16)(a0.y >> 16));
    xs[4] = bf2f((u16)a1.x); xs[5] = bf2f((u16)(a1.x >> 16));
    xs[6] = bf2f((u16)a1.y); xs[7] = bf2f((u16)(a1.y >> 16));
    float s1 = 0.f, s2 = 0.f;
#pragma unroll
    for (int j = 0; j < 8; ++j) { s1 += xs[j]; s2 += xs[j] * xs[j]; }
    for (int o = 32; o; o >>= 1) { s1 += __shfl_down(s1, o); s2 += __shfl_down(s2, o); }
    if ((tid & 63) == 0) { red[(tid >> 6) * 2] = s1; red[(tid >> 6) * 2 + 1] = s2; }
    __syncthreads();
    float S1 = red[0] + red[2] + red[4] + red[6];
    float S2 = red[1] + red[3] + red[5] + red[7];
    float mean = S1 * (1.f / 2048.f);
    float var = fmaxf(S2 * (1.f / 2048.f) - mean * mean, 0.f);
    float gs = g[s] * rsqrtf(var + 1e-5f);
    float bs = be[s];
    float y[8];
#pragma unroll
    for (int j = 0; j < 8; ++j) y[j] = (xs[j] - mean) * gs + bs;
    if (Yf) {
        *(float4*)&Yf[b0 + tid * 4] = make_float4(y[0], y[1], y[2], y[3]);
        *(float4*)&Yf[b1 + tid * 4] = make_float4(y[4], y[5], y[6], y[7]);
    } else {
        *(uint2*)&Y[b0 + tid * 4] = make_uint2(
            (u32)f2bf(y[0]) | ((u32)f2bf(y[1]) << 16),
            (u32)f2bf(y[2]) | ((u32)f2bf(y[3]) << 16));
        *(uint2*)&Y[b1 + tid * 4] = make_uint2(
            (u32)f2bf(y[4]) | ((u32)f2bf(y[5]) << 16),
            (u32)f2bf(y[6]) | ((u32)f2bf(y[7]) << 16));
    }
}

// ---------------------------------------------------------------------------
// One launch converts (f32 -> bf16) + transposes all 10 weight matrices of a
// layer into ws. s[0..5]: (16 heads)x(1024x64) QKV; s[6..7]: 1024x1024 Wo;
// s[8]: 1024x4096 W1; s[9]: 4096x1024 W2. 16384 blocks of 32x32 tiles.
// ---------------------------------------------------------------------------
struct TA { const float* s[10]; u16* d[10]; };

__global__ __launch_bounds__(256) void transpose_all(TA ta)
{
    __shared__ u16 tl[32][33];
    int id = blockIdx.x;
    const float* src; u16* dst; int Rr, Cc, tr, tc;
    if (id < 6144) {
        int wgt = id >> 10, rest = id & 1023;
        int head = rest >> 6, tile = rest & 63;
        tr = tile >> 1; tc = tile & 1; Rr = 1024; Cc = 64;
        src = ta.s[wgt] + head * 65536; dst = ta.d[wgt] + head * 65536;
    } else if (id < 8192) {
        int wgt = 6 + ((id - 6144) >> 10), rest = (id - 6144) & 1023;
        tr = rest >> 5; tc = rest & 31; Rr = 1024; Cc = 1024;
        src = ta.s[wgt]; dst = ta.d[wgt];
    } else if (id < 12288) {
        int rest = id - 8192;
        tr = rest >> 7; tc = rest & 127; Rr = 1024; Cc = 4096;
        src = ta.s[8]; dst = ta.d[8];
    } else {
        int rest = id - 12288;
        tr = rest >> 5; tc = rest & 31; Rr = 4096; Cc = 1024;
        src = ta.s[9]; dst = ta.d[9];
    }
    int r0 = tr * 32, c0 = tc * 32;
    int cl = threadIdx.x & 31, rl = threadIdx.x >> 5;
#pragma unroll
    for (int i = 0; i < 4; ++i)
        tl[rl + 8 * i][cl] = f2bf(src[(long)(r0 + rl + 8 * i) * Cc + c0 + cl]);
    __syncthreads();
#pragma unroll
    for (int i = 0; i < 4; ++i)
        dst[(long)(c0 + rl + 8 * i) * Rr + r0 + cl] = tl[cl][rl + 8 * i];
}

// ---------------------------------------------------------------------------
extern "C" void kernel_launch(void* const* d_in, const int* in_sizes, int n_in,
                              void* d_out, int out_size, void* d_ws, size_t ws_size,
                              hipStream_t stream)
{
    (void)in_sizes; (void)n_in; (void)out_size;
    const float* x   = (const float*)d_in[0];
    const float* Wq1 = (const float*)d_in[1];
    const float* bq1 = (const float*)d_in[2];
    const float* Wk1 = (const float*)d_in[3];
    const float* bk1 = (const float*)d_in[4];
    const float* Wv1 = (const float*)d_in[5];
    const float* bv1 = (const float*)d_in[6];
    const float* Wo1 = (const float*)d_in[7];
    const float* bo1 = (const float*)d_in[8];
    const float* Wq2 = (const float*)d_in[9];
    const float* bq2 = (const float*)d_in[10];
    const float* Wk2 = (const float*)d_in[11];
    const float* bk2 = (const float*)d_in[12];
    const float* Wv2 = (const float*)d_in[13];
    const float* bv2 = (const float*)d_in[14];
    const float* Wo2 = (const float*)d_in[15];
    const float* bo2 = (const float*)d_in[16];
    const float* g1  = (const float*)d_in[17];
    const float* be1 = (const float*)d_in[18];
    const float* g2  = (const float*)d_in[19];
    const float* be2 = (const float*)d_in[20];
    const float* g3  = (const float*)d_in[21];
    const float* be3 = (const float*)d_in[22];
    const float* W1  = (const float*)d_in[23];
    const float* bf1 = (const float*)d_in[24];
    const float* W2  = (const float*)d_in[25];
    const float* bf2 = (const float*)d_in[26];
    const int* maskp = (const int*)d_in[27];

    u16* ws = (u16*)d_ws;
    const size_t M1 = 1u << 20;
    u16* WT  = ws;             // 16M elems: transposed bf16 weights of current layer
    u16* QKV = ws + 16 * M1;   // 6M: fused QKV out, layout (h'=0..47, b, s, dk)
    u16* Vt  = ws + 22 * M1;   // 2M: V transposed (h, b, dk, s)
    u16* Ab  = ws + 24 * M1;   // 2M: attn out
    u16* X1  = ws + 26 * M1;
    u16* Yb  = ws + 28 * M1;
    u16* Hb  = ws + 30 * M1;   // bf16 hidden state (layer input)
    u16* HID = ws + 32 * M1;   // 8M elems
    if (ws_size < (size_t)(40 * M1) * sizeof(u16)) return;  // fail loud (poisoned out)

    // Split-K partials for FFN2 (f32, 2048x1024 = 4M u16 each). All four
    // regions are DEAD at FFN2 time: WT slots 0-7 (MHA weights, re-written by
    // next layer's transpose_all) and QKV/Vt (consumed by attn).
    P4 part = {{(float*)(WT + 0 * M1), (float*)(WT + 4 * M1),
                (float*)(QKV),         (float*)(QKV + 4 * M1)}};

    dim3 blk(256);
    dim3 g64(16, 32);      // O-proj: 64x64 tiles, 512 blocks (2/CU)
    dim3 gqkv(48, 16);     // fused QKV: N=3072, 128x64 tiles (768 blocks, 3/CU)
    dim3 gF1(64, 16);      // FFN1: N=4096, 128x64 tiles (1024 blocks, 4/CU)
    dim3 gF2(16, 32, 4);   // FFN2 split-K: 2048 blocks (~5/CU LDS-capped)
    dim3 gvt(32, 32);      // vtrans

    // x (f32) -> Hb (bf16)
    conv_f2b<<<dim3(2048), blk, 0, stream>>>(x, Hb);

    for (int l = 0; l < 4; ++l) {
        const u16* hin = Hb;

        TA ta;
        ta.s[0] = Wq1 + (size_t)l * M1;     ta.d[0] = WT + 0 * M1;
        ta.s[1] = Wk1 + (size_t)l * M1;     ta.d[1] = WT + 1 * M1;
        ta.s[2] = Wv1 + (size_t)l * M1;     ta.d[2] = WT + 2 * M1;
        ta.s[3] = Wq2 + (size_t)l * M1;     ta.d[3] = WT + 3 * M1;
        ta.s[4] = Wk2 + (size_t)l * M1;     ta.d[4] = WT + 4 * M1;
        ta.s[5] = Wv2 + (size_t)l * M1;     ta.d[5] = WT + 5 * M1;
        ta.s[6] = Wo1 + (size_t)l * M1;     ta.d[6] = WT + 6 * M1;
        ta.s[7] = Wo2 + (size_t)l * M1;     ta.d[7] = WT + 7 * M1;
        ta.s[8] = W1  + (size_t)l * 4 * M1; ta.d[8] = WT + 8 * M1;
        ta.s[9] = W2  + (size_t)l * 4 * M1; ta.d[9] = WT + 12 * M1;
        transpose_all<<<dim3(16384), blk, 0, stream>>>(ta);

        // ---- MHA1 (masked) ----
        B4 bQKV1 = {{bq1 + l * 1024, bk1 + l * 1024, bv1 + l * 1024, nullptr}};
        gemm_bt<128, 64><<<gqkv, blk, 0, stream>>>(hin, 1024, WT + 0 * M1, 1024, 65536,
            bQKV1, nullptr, QKV, 64, 65536, 131072, 1024, 0);
        vtrans<<<gvt, blk, 0, stream>>>(QKV + 4 * M1, Vt);
        attn_kernel<<<dim3(512), blk, 0, stream>>>(QKV, QKV + 2 * M1, Vt, Ab, maskp);
        B4 bO1 = {{bo1 + l * 1024, nullptr, nullptr, nullptr}};
        gemm_bt<64, 64><<<g64, blk, 0, stream>>>(Ab, 1024, WT + 6 * M1, 1024, 65536,
            bO1, hin, X1, 1024, 1048576, 64, 1024, 0);
        bn_kernel<<<dim3(1024), blk, 0, stream>>>(X1, X1, nullptr, g1 + l * 1024, be1 + l * 1024);

        // ---- MHA2 (unmasked, input x1, residual h) ----
        B4 bQKV2 = {{bq2 + l * 1024, bk2 + l * 1024, bv2 + l * 1024, nullptr}};
        gemm_bt<128, 64><<<gqkv, blk, 0, stream>>>(X1, 1024, WT + 3 * M1, 1024, 65536,
            bQKV2, nullptr, QKV, 64, 65536, 131072, 1024, 0);
        vtrans<<<gvt, blk, 0, stream>>>(QKV + 4 * M1, Vt);
        attn_kernel<<<dim3(512), blk, 0, stream>>>(QKV, QKV + 2 * M1, Vt, Ab, nullptr);
        B4 bO2 = {{bo2 + l * 1024, nullptr, nullptr, nullptr}};
        gemm_bt<64, 64><<<g64, blk, 0, stream>>>(Ab, 1024, WT + 7 * M1, 1024, 65536,
            bO2, hin, Yb, 1024, 1048576, 64, 1024, 0);
        bn_kernel<<<dim3(1024), blk, 0, stream>>>(Yb, Yb, nullptr, g2 + l * 1024, be2 + l * 1024);

        // ---- FFN (residual from x1) ----
        B4 bF1 = {{bf1 + l * 4096, bf1 + l * 4096 + 1024,
                   bf1 + l * 4096 + 2048, bf1 + l * 4096 + 3072}};
        gemm_bt<128, 64><<<gF1, blk, 0, stream>>>(Yb, 1024, WT + 8 * M1, 1024, 65536,
            bF1, nullptr, HID, 4096, 4194304, 64, 1024, 1);
        // FFN2: split-K=4 into f32 partials (WT slots 0-7 + QKV/Vt are dead),
        // then bn_merge = partial-sum + bias + X1 residual + BatchNorm(g3).
        gemm_splitk<<<gF2, blk, 0, stream>>>(HID, 4096, WT + 12 * M1, 4096, 262144, part);
        bn_merge<<<dim3(1024), blk, 0, stream>>>(part, bf2 + l * 1024, X1, Hb,
            (l == 3) ? (float*)d_out : nullptr, g3 + l * 1024, be3 + l * 1024);
    }
}